// Round 8
// baseline (126.633 us; speedup 1.0000x reference)
//
#include <hip/hip_runtime.h>
#include <stdint.h>

#define BATCH 2048
#define NNODE 4096
#define TDIM  2048
#define NCLS  10
#define WDIM  64
#define LCAP  256
#define LPAD  288   // LCAP padded to multiple of 32

typedef unsigned short u16;
typedef unsigned int   u32;

// ---------------- ws[k] = sum_w W[w][k]; also zero AdjTb sentinel row ----------------
__global__ void k_wsum(const float* __restrict__ w_sub, const float* __restrict__ w_inter,
                       float* __restrict__ wsum_sub, float* __restrict__ wsum_inter,
                       u32* __restrict__ AdjTb) {
  int k = blockIdx.x * blockDim.x + threadIdx.x;
  if (blockIdx.x == 0 && threadIdx.x < 64)
    AdjTb[(size_t)NNODE * 64 + threadIdx.x] = 0u;   // sentinel row k=4096: no bits
  if (k >= TDIM) return;
  float a = 0.f, b = 0.f;
  for (int w = 0; w < WDIM; ++w) {
    a += w_sub[w * TDIM + k];
    b += w_inter[w * TDIM + k];
  }
  wsum_sub[k] = a; wsum_inter[k] = b;
}

// ---- fused: adj bit-pack (Adjb rows, diag01, ballot-transposed AdjTb) + gvec ----
__global__ __launch_bounds__(256) void k_pack(
    const int* __restrict__ adj, const int* __restrict__ mask_idx,
    const float* __restrict__ gem, const float* __restrict__ wsum_sub,
    const float* __restrict__ wsum_inter,
    u32* __restrict__ Adjb, int* __restrict__ diag01, u32* __restrict__ AdjTb,
    float* __restrict__ g_sub, float* __restrict__ g_inter) {
  int bid = blockIdx.x, tid = threadIdx.x;
  if (bid < 2048) {
    __shared__ u16 tile[64][4];
    int nt = bid >> 6, kt = bid & 63;
    int nl = tid >> 2, kg = tid & 3;       // n-local, 16-k group (coalesced load layout)
    int n = nt * 64 + nl;
    int row = mask_idx[n];
    const uint4* src = (const uint4*)(adj + (size_t)row * NNODE + kt * 64 + kg * 16);
    uint4 v0 = src[0], v1 = src[1], v2 = src[2], v3 = src[3];
    unsigned m16 = 0;
    m16 |= (unsigned)(v0.x != 0u) << 0;  m16 |= (unsigned)(v0.y != 0u) << 1;
    m16 |= (unsigned)(v0.z != 0u) << 2;  m16 |= (unsigned)(v0.w != 0u) << 3;
    m16 |= (unsigned)(v1.x != 0u) << 4;  m16 |= (unsigned)(v1.y != 0u) << 5;
    m16 |= (unsigned)(v1.z != 0u) << 6;  m16 |= (unsigned)(v1.w != 0u) << 7;
    m16 |= (unsigned)(v2.x != 0u) << 8;  m16 |= (unsigned)(v2.y != 0u) << 9;
    m16 |= (unsigned)(v2.z != 0u) << 10; m16 |= (unsigned)(v2.w != 0u) << 11;
    m16 |= (unsigned)(v3.x != 0u) << 12; m16 |= (unsigned)(v3.y != 0u) << 13;
    m16 |= (unsigned)(v3.z != 0u) << 14; m16 |= (unsigned)(v3.w != 0u) << 15;
    unsigned other = (unsigned)__shfl((int)m16, (tid & 63) ^ 1, 64);
    if ((kg & 1) == 0)
      Adjb[n * 128 + kt * 2 + (kg >> 1)] = m16 | (other << 16);
    if ((row >> 4) == (kt * 4 + kg))
      diag01[n] = (int)((m16 >> (row & 15)) & 1u);
    tile[nl][kg] = (u16)m16;
    __syncthreads();
    // ballot-transpose: wave wid handles k-group wid; lane = n-local
    int lane = tid & 63, wid = tid >> 6;
    unsigned mm = tile[lane][wid];
    #pragma unroll
    for (int j = 0; j < 16; ++j) {
      unsigned long long bal = __ballot((mm >> j) & 1u);
      if (lane == 0) {
        int k = kt * 64 + wid * 16 + j;
        *(uint2*)&AdjTb[(size_t)k * 64 + nt * 2] =
            make_uint2((u32)bal, (u32)(bal >> 32));
      }
    }
  } else {
    // gvec: g[n] = gem[n,:] . wsum
    int b2 = bid - 2048;
    int wid = tid >> 6, lane = tid & 63;
    int n = b2 * 4 + wid;
    const float4* rowv = (const float4*)(gem + (size_t)n * TDIM);
    const float4* ws4 = (const float4*)wsum_sub;
    const float4* wi4 = (const float4*)wsum_inter;
    float a = 0.f, b = 0.f;
    #pragma unroll
    for (int s = 0; s < TDIM / 256; ++s) {
      int idx = s * 64 + lane;
      float4 g = rowv[idx], u = ws4[idx], v = wi4[idx];
      a += g.x * u.x + g.y * u.y + g.z * u.z + g.w * u.w;
      b += g.x * v.x + g.y * v.y + g.z * v.z + g.w * v.w;
    }
    #pragma unroll
    for (int off = 32; off > 0; off >>= 1) {
      a += __shfl_down(a, off, 64);
      b += __shfl_down(b, off, 64);
    }
    if (lane == 0) { g_sub[n] = a; g_inter[n] = b; }
  }
}

// ---- misc (8 x 1024): class counts -> invN, svec; cvec; predT transpose ----
__global__ __launch_bounds__(1024) void k_misc(
    const float* __restrict__ pred, const int* __restrict__ target,
    const int* __restrict__ mask_idx, const int* __restrict__ diag01,
    const float* __restrict__ g_sub,
    float* __restrict__ invN, float* __restrict__ svec,
    float* __restrict__ cvec, float* __restrict__ predT) {
  __shared__ int cnt[NCLS];
  int tid = threadIdx.x, lane = tid & 63;
  if (tid < NCLS) cnt[tid] = 0;
  __syncthreads();
  #pragma unroll
  for (int i = 0; i < BATCH / 1024; ++i) {
    int t = target[tid + i * 1024];
    #pragma unroll
    for (int c = 0; c < NCLS; ++c) {
      unsigned long long m = __ballot(t == c);
      if (lane == 0 && m) atomicAdd(&cnt[c], __popcll(m));
    }
  }
  __syncthreads();
  int nl = tid & 255, cg = tid >> 8;           // 4 class-groups
  int n = blockIdx.x * 256 + nl;
  int t = target[n];
  for (int c = cg; c < NCLS; c += 4)
    predT[c * BATCH + n] = pred[n * NCLS + c];
  if (cg == 0) {
    invN[n] = 1.f / (float)cnt[t];
    svec[n] = pred[n * NCLS + t];
    cvec[n] = diag01[n] ? 0.f : g_sub[mask_idx[n]];
  }
}

// ---------- main: popc list build -> wave-per-k ds_add scatter -> loss ----------
__global__ __launch_bounds__(256) void k_main(
    const u32* __restrict__ Adjb, const u32* __restrict__ AdjTb,
    const int* __restrict__ target,
    const float* __restrict__ g_sub, const float* __restrict__ g_inter,
    const float* __restrict__ cvec, const float* __restrict__ invN,
    const float* __restrict__ svec, const float* __restrict__ predT,
    const int* __restrict__ mask_idx, float* __restrict__ partial) {
  __shared__ __align__(16) float S1[2048];
  __shared__ __align__(16) float S2[2048];
  __shared__ u16 abit[256];
  __shared__ u16 list_s[LPAD];
  __shared__ float2 gpair[LPAD];
  __shared__ int wcnt[4];
  __shared__ float wred[4];
  __shared__ float rowsum_sh;

  int tid = threadIdx.x, p = blockIdx.x;
  int lane = tid & 63, wid = tid >> 6;

  // P1: load packed row bits (tid<128), publish halfwords, zero S
  u32 w = 0;
  if (tid < 128) {
    w = Adjb[p * 128 + tid];
    abit[2 * tid]     = (u16)(w & 0xFFFFu);
    abit[2 * tid + 1] = (u16)(w >> 16);
  }
  float4 z4 = make_float4(0.f, 0.f, 0.f, 0.f);
  ((float4*)S1)[tid] = z4; ((float4*)S1)[tid + 256] = z4;
  ((float4*)S2)[tid] = z4; ((float4*)S2)[tid + 256] = z4;
  int cnt = __popc(w);
  int incl = cnt;
  #pragma unroll
  for (int d = 1; d < 64; d <<= 1) {
    int y = __shfl_up(incl, d, 64);
    if (lane >= d) incl += y;
  }
  if (lane == 63) wcnt[wid] = incl;
  __syncthreads();                                   // b1
  int wbase = 0;
  #pragma unroll
  for (int ww = 0; ww < 4; ++ww) if (ww < wid) wbase += wcnt[ww];
  int off = wbase + incl - cnt;
  u32 r = w; int kb = tid * 32;
  while (r) {
    int j = __ffs(r) - 1; r &= r - 1;
    if (off < LCAP) list_s[off] = (u16)(kb + j);
    ++off;
  }
  int total = wcnt[0] + wcnt[1] + wcnt[2] + wcnt[3];
  if (total > LCAP) total = LCAP;
  int totalPad = (total + 31) & ~31;                 // multiple of 32 (4 waves x 8)
  __syncthreads();                                   // b2

  // P3: stage g pairs (+ sentinel pad) + rowsum
  float rl = 0.f;
  for (int i = tid; i < totalPad; i += 256) {
    float2 g2 = make_float2(0.f, 0.f);
    if (i < total) {
      int k = list_s[i];
      g2.x = g_sub[k]; g2.y = g_inter[k];
      rl += g2.x;
    } else {
      list_s[i] = (u16)4096;                         // sentinel -> zero AdjTb row
    }
    gpair[i] = g2;
  }
  #pragma unroll
  for (int o = 32; o > 0; o >>= 1) rl += __shfl_down(rl, o, 64);
  if (lane == 0) wred[wid] = rl;
  __syncthreads();                                   // b3
  if (tid == 0) rowsum_sh = wred[0] + wred[1] + wred[2] + wred[3];

  // P4: wave-per-k scatter. Lane owns n in [32*lane, 32*lane+32) via its own word.
  // ds_add_f32 (atomicAdd on LDS, return unused) = fire-and-forget, no RMW chain.
  for (int s0 = 0; s0 < totalPad; s0 += 32) {
    u32 wv[8]; float2 gg[8];
    #pragma unroll
    for (int u = 0; u < 8; ++u) {
      int it = s0 + u * 4 + wid;
      int k = list_s[it];
      gg[u] = gpair[it];
      wv[u] = AdjTb[k * 64 + lane];
    }
    #pragma unroll
    for (int u = 0; u < 8; ++u) {
      u32 b = wv[u];
      float gx = gg[u].x, gy = gg[u].y;
      while (b) {
        int j = __ffs(b) - 1; b &= b - 1;
        int n = lane * 32 + j;
        atomicAdd(&S1[n], gx);
        atomicAdd(&S2[n], gy);
      }
    }
  }
  __syncthreads();                                   // b4

  // P5: loss epilogue (vectorized loads, S from LDS)
  int tp = target[p];
  float sp = svec[p], ip = invN[p], rs = rowsum_sh;
  int n0 = tid * 8;
  int tn[8], mn[8];
  float iN[8], cv[8], pr[8], s1[8], s2[8];
  *(int4*)(tn)       = *(const int4*)&target[n0];
  *(int4*)(tn + 4)   = *(const int4*)&target[n0 + 4];
  *(int4*)(mn)       = *(const int4*)&mask_idx[n0];
  *(int4*)(mn + 4)   = *(const int4*)&mask_idx[n0 + 4];
  *(float4*)(iN)     = *(const float4*)&invN[n0];
  *(float4*)(iN + 4) = *(const float4*)&invN[n0 + 4];
  *(float4*)(cv)     = *(const float4*)&cvec[n0];
  *(float4*)(cv + 4) = *(const float4*)&cvec[n0 + 4];
  *(float4*)(pr)     = *(const float4*)&predT[tp * BATCH + n0];
  *(float4*)(pr + 4) = *(const float4*)&predT[tp * BATCH + n0 + 4];
  *(float4*)(s1)     = *(const float4*)&S1[n0];
  *(float4*)(s1 + 4) = *(const float4*)&S1[n0 + 4];
  *(float4*)(s2)     = *(const float4*)&S2[n0];
  *(float4*)(s2 + 4) = *(const float4*)&S2[n0 + 4];
  float acc = 0.f;
  #pragma unroll
  for (int j = 0; j < 8; ++j) {
    if (tn[j] == tp) continue;
    float apn = ((abit[mn[j] >> 4] >> (mn[j] & 15)) & 1) ? 1.f : 0.f;
    float vs = rs - s1[j] - apn * cv[j];
    float rr = (1.f + vs) * __builtin_amdgcn_rcpf(1.f + s2[j]);
    float v = __builtin_amdgcn_rcpf(1.f + __expf(rr));   // 1 - sigmoid(rr)
    float d = 1.f - (sp - pr[j]);
    acc += ip * iN[j] * v * d * d;
  }
  #pragma unroll
  for (int o = 32; o > 0; o >>= 1) acc += __shfl_down(acc, o, 64);
  if (lane == 0) wred[wid] = acc;
  __syncthreads();                                   // b5
  if (tid == 0) partial[p] = wred[0] + wred[1] + wred[2] + wred[3];
}

__global__ void k_final(const float* __restrict__ partial, float* __restrict__ out) {
  int tid = threadIdx.x;  // 256
  float local = 0.f;
  for (int p = tid; p < BATCH; p += 256) local += partial[p];
  __shared__ float red[4];
  #pragma unroll
  for (int off = 32; off > 0; off >>= 1) local += __shfl_down(local, off, 64);
  if ((tid & 63) == 0) red[tid >> 6] = local;
  __syncthreads();
  if (tid == 0) out[0] = red[0] + red[1] + red[2] + red[3];
}

extern "C" void kernel_launch(void* const* d_in, const int* in_sizes, int n_in,
                              void* d_out, int out_size, void* d_ws, size_t ws_size,
                              hipStream_t stream) {
  const float* pred    = (const float*)d_in[0];
  const float* gem     = (const float*)d_in[1];
  const float* w_sub   = (const float*)d_in[2];
  const float* w_inter = (const float*)d_in[3];
  // d_in[4] = w_global (unused by the loss)
  const int* adj       = (const int*)d_in[5];   // bool in reference -> int32
  const int* target    = (const int*)d_in[6];
  const int* mask_idx  = (const int*)d_in[7];
  float* out = (float*)d_out;

  char* ws = (char*)d_ws;
  size_t off = 0;
  auto alloc = [&](size_t bytes) {
    void* p = ws + off;
    off = (off + bytes + 255) & ~(size_t)255;
    return p;
  };
  u32*   Adjb     = (u32*)alloc((size_t)BATCH * 128 * 4);          // 1 MB
  u32*   AdjTb    = (u32*)alloc((size_t)(NNODE + 1) * 64 * 4);     // 1 MB + sentinel
  int*   diag01   = (int*)alloc((size_t)BATCH * 4);
  float* predT    = (float*)alloc((size_t)NCLS * BATCH * 4);       // 80 KB
  float* g_sub    = (float*)alloc((size_t)NNODE * 4);
  float* g_inter  = (float*)alloc((size_t)NNODE * 4);
  float* wsum_sub = (float*)alloc((size_t)TDIM * 4);
  float* wsum_inter=(float*)alloc((size_t)TDIM * 4);
  float* cvec     = (float*)alloc((size_t)BATCH * 4);
  float* invN     = (float*)alloc((size_t)BATCH * 4);
  float* svec     = (float*)alloc((size_t)BATCH * 4);
  float* partial  = (float*)alloc((size_t)BATCH * 4);

  k_wsum<<<(TDIM + 255) / 256, 256, 0, stream>>>(w_sub, w_inter, wsum_sub, wsum_inter, AdjTb);
  k_pack<<<2048 + NNODE / 4, 256, 0, stream>>>(adj, mask_idx, gem, wsum_sub, wsum_inter,
                                               Adjb, diag01, AdjTb, g_sub, g_inter);
  k_misc<<<BATCH / 256, 1024, 0, stream>>>(pred, target, mask_idx, diag01, g_sub,
                                           invN, svec, cvec, predT);
  k_main<<<BATCH, 256, 0, stream>>>(Adjb, AdjTb, target, g_sub, g_inter,
                                    cvec, invN, svec, predT, mask_idx, partial);
  k_final<<<1, 256, 0, stream>>>(partial, out);
}

// Round 9
// 69.150 us; speedup vs baseline: 1.8313x; 1.8313x over previous
//
#include <hip/hip_runtime.h>
#include <stdint.h>

#define BATCH 2048
#define NNODE 4096
#define TDIM  2048
#define NCLS  10
#define WDIM  64
#define LCAP  256
#define LPAD  264   // LCAP + 8 pad

typedef unsigned short u16;
typedef unsigned int   u32;
typedef unsigned long long u64;

// ---------------- ws[k] = sum_w W[w][k]; also zero AdjTb sentinel row ----------------
__global__ void k_wsum(const float* __restrict__ w_sub, const float* __restrict__ w_inter,
                       float* __restrict__ wsum_sub, float* __restrict__ wsum_inter,
                       u32* __restrict__ AdjTb) {
  int k = blockIdx.x * blockDim.x + threadIdx.x;
  if (blockIdx.x == 0 && threadIdx.x < 64)
    AdjTb[(size_t)NNODE * 64 + threadIdx.x] = 0u;   // sentinel row k=4096: no bits
  if (k >= TDIM) return;
  float a = 0.f, b = 0.f;
  for (int w = 0; w < WDIM; ++w) {
    a += w_sub[w * TDIM + k];
    b += w_inter[w * TDIM + k];
  }
  wsum_sub[k] = a; wsum_inter[k] = b;
}

// ---- fused: adj bit-pack (Adjb rows, diag01, ballot-transposed AdjTb) + gvec ----
__global__ __launch_bounds__(256) void k_pack(
    const int* __restrict__ adj, const int* __restrict__ mask_idx,
    const float* __restrict__ gem, const float* __restrict__ wsum_sub,
    const float* __restrict__ wsum_inter,
    u32* __restrict__ Adjb, int* __restrict__ diag01, u32* __restrict__ AdjTb,
    float* __restrict__ g_sub, float* __restrict__ g_inter) {
  int bid = blockIdx.x, tid = threadIdx.x;
  if (bid < 2048) {
    __shared__ u16 tile[64][4];
    int nt = bid >> 6, kt = bid & 63;
    int nl = tid >> 2, kg = tid & 3;       // n-local, 16-k group (coalesced load layout)
    int n = nt * 64 + nl;
    int row = mask_idx[n];
    const uint4* src = (const uint4*)(adj + (size_t)row * NNODE + kt * 64 + kg * 16);
    uint4 v0 = src[0], v1 = src[1], v2 = src[2], v3 = src[3];
    unsigned m16 = 0;
    m16 |= (unsigned)(v0.x != 0u) << 0;  m16 |= (unsigned)(v0.y != 0u) << 1;
    m16 |= (unsigned)(v0.z != 0u) << 2;  m16 |= (unsigned)(v0.w != 0u) << 3;
    m16 |= (unsigned)(v1.x != 0u) << 4;  m16 |= (unsigned)(v1.y != 0u) << 5;
    m16 |= (unsigned)(v1.z != 0u) << 6;  m16 |= (unsigned)(v1.w != 0u) << 7;
    m16 |= (unsigned)(v2.x != 0u) << 8;  m16 |= (unsigned)(v2.y != 0u) << 9;
    m16 |= (unsigned)(v2.z != 0u) << 10; m16 |= (unsigned)(v2.w != 0u) << 11;
    m16 |= (unsigned)(v3.x != 0u) << 12; m16 |= (unsigned)(v3.y != 0u) << 13;
    m16 |= (unsigned)(v3.z != 0u) << 14; m16 |= (unsigned)(v3.w != 0u) << 15;
    unsigned other = (unsigned)__shfl((int)m16, (tid & 63) ^ 1, 64);
    if ((kg & 1) == 0)
      Adjb[n * 128 + kt * 2 + (kg >> 1)] = m16 | (other << 16);
    if ((row >> 4) == (kt * 4 + kg))
      diag01[n] = (int)((m16 >> (row & 15)) & 1u);
    tile[nl][kg] = (u16)m16;
    __syncthreads();
    // ballot-transpose: wave wid handles k-group wid; lane = n-local
    int lane = tid & 63, wid = tid >> 6;
    unsigned mm = tile[lane][wid];
    #pragma unroll
    for (int j = 0; j < 16; ++j) {
      unsigned long long bal = __ballot((mm >> j) & 1u);
      if (lane == 0) {
        int k = kt * 64 + wid * 16 + j;
        *(uint2*)&AdjTb[(size_t)k * 64 + nt * 2] =
            make_uint2((u32)bal, (u32)(bal >> 32));
      }
    }
  } else {
    // gvec: g[n] = gem[n,:] . wsum
    int b2 = bid - 2048;
    int wid = tid >> 6, lane = tid & 63;
    int n = b2 * 4 + wid;
    const float4* rowv = (const float4*)(gem + (size_t)n * TDIM);
    const float4* ws4 = (const float4*)wsum_sub;
    const float4* wi4 = (const float4*)wsum_inter;
    float a = 0.f, b = 0.f;
    #pragma unroll
    for (int s = 0; s < TDIM / 256; ++s) {
      int idx = s * 64 + lane;
      float4 g = rowv[idx], u = ws4[idx], v = wi4[idx];
      a += g.x * u.x + g.y * u.y + g.z * u.z + g.w * u.w;
      b += g.x * v.x + g.y * v.y + g.z * v.z + g.w * v.w;
    }
    #pragma unroll
    for (int off = 32; off > 0; off >>= 1) {
      a += __shfl_down(a, off, 64);
      b += __shfl_down(b, off, 64);
    }
    if (lane == 0) { g_sub[n] = a; g_inter[n] = b; }
  }
}

// ---- misc (8 x 1024): class counts -> invN, svec; cvec; predT transpose ----
__global__ __launch_bounds__(1024) void k_misc(
    const float* __restrict__ pred, const int* __restrict__ target,
    const int* __restrict__ mask_idx, const int* __restrict__ diag01,
    const float* __restrict__ g_sub,
    float* __restrict__ invN, float* __restrict__ svec,
    float* __restrict__ cvec, float* __restrict__ predT) {
  __shared__ int cnt[NCLS];
  int tid = threadIdx.x, lane = tid & 63;
  if (tid < NCLS) cnt[tid] = 0;
  __syncthreads();
  #pragma unroll
  for (int i = 0; i < BATCH / 1024; ++i) {
    int t = target[tid + i * 1024];
    #pragma unroll
    for (int c = 0; c < NCLS; ++c) {
      unsigned long long m = __ballot(t == c);
      if (lane == 0 && m) atomicAdd(&cnt[c], __popcll(m));
    }
  }
  __syncthreads();
  int nl = tid & 255, cg = tid >> 8;           // 4 class-groups
  int n = blockIdx.x * 256 + nl;
  int t = target[n];
  for (int c = cg; c < NCLS; c += 4)
    predT[c * BATCH + n] = pred[n * NCLS + c];
  if (cg == 0) {
    invN[n] = 1.f / (float)cnt[t];
    svec[n] = pred[n * NCLS + t];
    cvec[n] = diag01[n] ? 0.f : g_sub[mask_idx[n]];
  }
}

// ------- main: list build -> flattened 64-bit-mask owned-slot scatter -> loss -------
__global__ __launch_bounds__(256) void k_main(
    const u32* __restrict__ Adjb, const u32* __restrict__ AdjTb,
    const int* __restrict__ target,
    const float* __restrict__ g_sub, const float* __restrict__ g_inter,
    const float* __restrict__ cvec, const float* __restrict__ invN,
    const float* __restrict__ svec, const float* __restrict__ predT,
    const int* __restrict__ mask_idx, float* __restrict__ partial) {
  __shared__ __align__(16) float2 S[2048];     // interleaved {s_sub, s_inter}, slot owned by thread n>>3
  __shared__ u16 abit[256];
  __shared__ u16 list_s[LPAD];
  __shared__ float2 gpair[LPAD];
  __shared__ int wcnt[4];
  __shared__ float wred[4];
  __shared__ float rowsum_sh;

  int tid = threadIdx.x, p = blockIdx.x;
  int lane = tid & 63, wid = tid >> 6;

  // P1: load packed row bits (tid<128), publish halfwords, zero S
  u32 w = 0;
  if (tid < 128) {
    w = Adjb[p * 128 + tid];
    abit[2 * tid]     = (u16)(w & 0xFFFFu);
    abit[2 * tid + 1] = (u16)(w >> 16);
  }
  float4 z4 = make_float4(0.f, 0.f, 0.f, 0.f);
  #pragma unroll
  for (int i = 0; i < 4; ++i)
    ((float4*)S)[tid + i * 256] = z4;
  int cnt = __popc(w);
  int incl = cnt;
  #pragma unroll
  for (int d = 1; d < 64; d <<= 1) {
    int y = __shfl_up(incl, d, 64);
    if (lane >= d) incl += y;
  }
  if (lane == 63) wcnt[wid] = incl;
  __syncthreads();                                   // b1
  int wbase = 0;
  #pragma unroll
  for (int ww = 0; ww < 4; ++ww) if (ww < wid) wbase += wcnt[ww];
  int off = wbase + incl - cnt;
  u32 r = w; int kb = tid * 32;
  while (r) {
    int j = __ffs(r) - 1; r &= r - 1;
    if (off < LCAP) list_s[off] = (u16)(kb + j);
    ++off;
  }
  int total = wcnt[0] + wcnt[1] + wcnt[2] + wcnt[3];
  if (total > LCAP) total = LCAP;
  int totalPad = (total + 7) & ~7;
  __syncthreads();                                   // b2

  // P3: stage g pairs (+ sentinel pad) + rowsum
  float rl = 0.f;
  for (int i = tid; i < totalPad; i += 256) {
    float2 g2 = make_float2(0.f, 0.f);
    if (i < total) {
      int k = list_s[i];
      g2.x = g_sub[k]; g2.y = g_inter[k];
      rl += g2.x;
    } else {
      list_s[i] = (u16)4096;                         // sentinel -> zero AdjTb row
    }
    gpair[i] = g2;
  }
  #pragma unroll
  for (int o = 32; o > 0; o >>= 1) rl += __shfl_down(rl, o, 64);
  if (lane == 0) wred[wid] = rl;
  __syncthreads();                                   // b3
  if (tid == 0) rowsum_sh = wred[0] + wred[1] + wred[2] + wred[3];

  // P4: flattened-mask scatter. Thread owns slots [8*tid, 8*tid+8).
  // Per 8-k batch: pack this thread's byte from each of 8 AdjTb words into one
  // u64; one while(ffsll) visits only real bits (kk = bit>>3, slot = bit&7).
  const u32* At = AdjTb + (tid >> 2);
  int sh = (tid & 3) * 8;
  int nbase = tid * 8;
  for (int s0 = 0; s0 < totalPad; s0 += 8) {
    u32 wv[8];
    #pragma unroll
    for (int u = 0; u < 8; ++u) {
      int k = list_s[s0 + u];
      wv[u] = At[k * 64];
    }
    u32 lo = 0, hi = 0;
    #pragma unroll
    for (int u = 0; u < 4; ++u) {
      lo |= ((wv[u] >> sh) & 0xFFu) << (8 * u);
      hi |= ((wv[u + 4] >> sh) & 0xFFu) << (8 * u);
    }
    u64 m = (u64)lo | ((u64)hi << 32);
    while (m) {
      int j = __ffsll(m) - 1; m &= m - 1;
      int kk = j >> 3, slot = j & 7;
      float2 g = gpair[s0 + kk];
      float2 v = S[nbase + slot];
      v.x += g.x; v.y += g.y;
      S[nbase + slot] = v;
    }
  }
  __syncthreads();                                   // b4

  // P5: loss epilogue (vectorized loads, S from LDS)
  int tp = target[p];
  float sp = svec[p], ip = invN[p], rs = rowsum_sh;
  int n0 = tid * 8;
  int tn[8], mn[8];
  float iN[8], cv[8], pr[8];
  float2 s12[8];
  *(int4*)(tn)       = *(const int4*)&target[n0];
  *(int4*)(tn + 4)   = *(const int4*)&target[n0 + 4];
  *(int4*)(mn)       = *(const int4*)&mask_idx[n0];
  *(int4*)(mn + 4)   = *(const int4*)&mask_idx[n0 + 4];
  *(float4*)(iN)     = *(const float4*)&invN[n0];
  *(float4*)(iN + 4) = *(const float4*)&invN[n0 + 4];
  *(float4*)(cv)     = *(const float4*)&cvec[n0];
  *(float4*)(cv + 4) = *(const float4*)&cvec[n0 + 4];
  *(float4*)(pr)     = *(const float4*)&predT[tp * BATCH + n0];
  *(float4*)(pr + 4) = *(const float4*)&predT[tp * BATCH + n0 + 4];
  #pragma unroll
  for (int q = 0; q < 4; ++q)
    *(float4*)&s12[q * 2] = *(const float4*)&S[n0 + q * 2];
  float acc = 0.f;
  #pragma unroll
  for (int j = 0; j < 8; ++j) {
    if (tn[j] == tp) continue;
    float apn = ((abit[mn[j] >> 4] >> (mn[j] & 15)) & 1) ? 1.f : 0.f;
    float vs = rs - s12[j].x - apn * cv[j];
    float rr = (1.f + vs) * __builtin_amdgcn_rcpf(1.f + s12[j].y);
    float v = __builtin_amdgcn_rcpf(1.f + __expf(rr));   // 1 - sigmoid(rr)
    float d = 1.f - (sp - pr[j]);
    acc += ip * iN[j] * v * d * d;
  }
  #pragma unroll
  for (int o = 32; o > 0; o >>= 1) acc += __shfl_down(acc, o, 64);
  if (lane == 0) wred[wid] = acc;
  __syncthreads();                                   // b5
  if (tid == 0) partial[p] = wred[0] + wred[1] + wred[2] + wred[3];
}

__global__ void k_final(const float* __restrict__ partial, float* __restrict__ out) {
  int tid = threadIdx.x;  // 256
  float local = 0.f;
  for (int p = tid; p < BATCH; p += 256) local += partial[p];
  __shared__ float red[4];
  #pragma unroll
  for (int off = 32; off > 0; off >>= 1) local += __shfl_down(local, off, 64);
  if ((tid & 63) == 0) red[tid >> 6] = local;
  __syncthreads();
  if (tid == 0) out[0] = red[0] + red[1] + red[2] + red[3];
}

extern "C" void kernel_launch(void* const* d_in, const int* in_sizes, int n_in,
                              void* d_out, int out_size, void* d_ws, size_t ws_size,
                              hipStream_t stream) {
  const float* pred    = (const float*)d_in[0];
  const float* gem     = (const float*)d_in[1];
  const float* w_sub   = (const float*)d_in[2];
  const float* w_inter = (const float*)d_in[3];
  // d_in[4] = w_global (unused by the loss)
  const int* adj       = (const int*)d_in[5];   // bool in reference -> int32
  const int* target    = (const int*)d_in[6];
  const int* mask_idx  = (const int*)d_in[7];
  float* out = (float*)d_out;

  char* ws = (char*)d_ws;
  size_t off = 0;
  auto alloc = [&](size_t bytes) {
    void* p = ws + off;
    off = (off + bytes + 255) & ~(size_t)255;
    return p;
  };
  u32*   Adjb     = (u32*)alloc((size_t)BATCH * 128 * 4);          // 1 MB
  u32*   AdjTb    = (u32*)alloc((size_t)(NNODE + 1) * 64 * 4);     // 1 MB + sentinel
  int*   diag01   = (int*)alloc((size_t)BATCH * 4);
  float* predT    = (float*)alloc((size_t)NCLS * BATCH * 4);       // 80 KB
  float* g_sub    = (float*)alloc((size_t)NNODE * 4);
  float* g_inter  = (float*)alloc((size_t)NNODE * 4);
  float* wsum_sub = (float*)alloc((size_t)TDIM * 4);
  float* wsum_inter=(float*)alloc((size_t)TDIM * 4);
  float* cvec     = (float*)alloc((size_t)BATCH * 4);
  float* invN     = (float*)alloc((size_t)BATCH * 4);
  float* svec     = (float*)alloc((size_t)BATCH * 4);
  float* partial  = (float*)alloc((size_t)BATCH * 4);

  k_wsum<<<(TDIM + 255) / 256, 256, 0, stream>>>(w_sub, w_inter, wsum_sub, wsum_inter, AdjTb);
  k_pack<<<2048 + NNODE / 4, 256, 0, stream>>>(adj, mask_idx, gem, wsum_sub, wsum_inter,
                                               Adjb, diag01, AdjTb, g_sub, g_inter);
  k_misc<<<BATCH / 256, 1024, 0, stream>>>(pred, target, mask_idx, diag01, g_sub,
                                           invN, svec, cvec, predT);
  k_main<<<BATCH, 256, 0, stream>>>(Adjb, AdjTb, target, g_sub, g_inter,
                                    cvec, invN, svec, predT, mask_idx, partial);
  k_final<<<1, 256, 0, stream>>>(partial, out);
}